// Round 13
// baseline (364.384 us; speedup 1.0000x reference)
//
#include <hip/hip_runtime.h>
#include <cstdint>

// Problem constants (fixed by the reference setup_inputs)
#define BB    2
#define LL    2048
#define HH    8
#define EE    64
#define DIAG  64
#define RR    16         // output rows per compute block
#define WCAP  144        // staged window rows: jrel 0..143 <-> j = i0-64 .. i0+79
#define SKB   36         // bf16 tile row stride in DWORDS (32 data + 4 pad)
#define PS    148        // prob-row stride (floats), jrel-absolute layout
#define NT    256        // threads per block (4 waves)

// Grid 4096: even blockIdx = compute block (R10 structure, window stores only),
// odd blockIdx = zero block (pure streaming stores of the out-of-window zeros).
// Zero and compute blocks co-reside on every CU (parity interleave), so the
// HBM write pipe drains zeros continuously while compute blocks do DS/VALU
// work — de-phasing via TLP, immune to in-order waitcnt stalls (R12 lesson:
// program-order early stores are defeated by the staging loads' vmcnt wait).
//
// SPILL LESSON (R4-R7): keep the 2-row/4-accumulator Phase-B shape.
// WRITE-ONCE (R4): zero/window split is 64B line-aligned and disjoint.
__global__ __launch_bounds__(NT, 4) void anomaly_attn_kernel(
    const float* __restrict__ Q,   // [B, L, H, E]
    const float* __restrict__ K,   // [B, L, H, E]
    const float* __restrict__ V,   // [B, L, H, E]
    float* __restrict__ outV,      // [B, L, H, E]
    float* __restrict__ outS)      // [B, H, L, L]
{
    __shared__ unsigned lds_kv[WCAP * SKB];  // bf16 K tile, later V tile (20.7 KB)
    __shared__ float    lds_q[RR * EE];      // Q tile fp32 (4 KB)
    __shared__ float    lds_sp[RR * PS];     // probs fp32, jrel-absolute (9.25 KB)
    // total ~34 KB -> 4 blocks/CU (mixed compute+zero residency)

    const int bid  = blockIdx.x;
    const int cb   = bid >> 1;                       // row-block id [0, 2048)
    // XCD swizzle: contiguous row-blocks per XCD for K/V L2 locality.
    const int gblk = (cb & 7) * 256 + (cb >> 3);     // [0, 2048)
    const int rb   = gblk & 127;
    const int h    = (gblk >> 7) & 7;
    const int b    = gblk >> 10;
    const int i0   = rb * RR;

    const int t    = threadIdx.x;

    const int j0  = i0 - 64;          // jrel 0 <-> j = i0 - 64 (16-float aligned)
    const int j04 = j0 >> 2;
    const int wstart4 = j04 < 0 ? 0 : j04;
    int wend4 = j04 + 36; if (wend4 > LL / 4) wend4 = LL / 4;
    const int wwid4  = wend4 - wstart4;
    const int nzero4 = LL / 4 - wwid4;

    float* srow0 = outS + (((size_t)(b * HH + h)) * LL + i0) * LL;

    // ================= ZERO BLOCK: stream zeros, exit. =================
    if (bid & 1) {
        const float4 z = make_float4(0.f, 0.f, 0.f, 0.f);
        for (int row = 0; row < RR; ++row) {
            float4* srow4 = (float4*)(srow0 + (size_t)row * LL);
            for (int c = t; c < nzero4; c += NT) {
                const int col4 = c < wstart4 ? c : c + wwid4;
                srow4[col4] = z;   // disjoint from the window region
            }
        }
        return;
    }

    // ================= COMPUTE BLOCK (R10 structure) =================
    const int wave = t >> 6;
    const int lane = t & 63;
    const size_t headOff = ((size_t)b * LL * HH + h) * EE;
    const int    rowStr  = HH * EE;   // 512 floats between sequence rows

    // bf16 helpers (round-to-nearest-even pack; shift unpack)
    auto pack2 = [](float x, float y) -> unsigned {
        unsigned ux = __float_as_uint(x);
        unsigned uy = __float_as_uint(y);
        unsigned bx = (ux + 0x7FFFu + ((ux >> 16) & 1u)) >> 16;
        unsigned by = (uy + 0x7FFFu + ((uy >> 16) & 1u)) >> 16;
        return bx | (by << 16);
    };
    auto lo = [](unsigned u) -> float { return __uint_as_float(u << 16); };
    auto hi = [](unsigned u) -> float { return __uint_as_float(u & 0xFFFF0000u); };

    // ---- Phase P: zero this wave's 4 prob rows (wave-local) ----
    {
        const float4 z4 = make_float4(0.f, 0.f, 0.f, 0.f);
        float4* zp = (float4*)(lds_sp + wave * 4 * PS);
        for (int z = lane; z < PS; z += 64) zp[z] = z4;
    }

    // ---- Phase A: stage Q tile (fp32) + K window (bf16, rows clamped) ----
    {
        const int qrow = t >> 4, qf = t & 15;
        *(float4*)(lds_q + qrow * EE + qf * 4) =
            *(const float4*)(Q + headOff + (size_t)(i0 + qrow) * rowStr + qf * 4);
        for (int idx = t; idx < WCAP * 16; idx += NT) {
            const int trow = idx >> 4, tf = idx & 15;
            int j = j0 + trow; j = j < 0 ? 0 : (j > LL - 1 ? LL - 1 : j);
            const float4 kv = *(const float4*)(K + headOff + (size_t)j * rowStr + tf * 4);
            uint2 pk; pk.x = pack2(kv.x, kv.y); pk.y = pack2(kv.z, kv.w);
            *(uint2*)(lds_kv + trow * SKB + tf * 2) = pk;
        }
    }
    __syncthreads();

    // ---- Phase B: scores + softmax, 2-row passes sharing K reads.       ----
    const float scale = 0.125f;   // 1/sqrt(64)
#pragma unroll
    for (int p = 0; p < 2; ++p) {
        const int rA = wave * 4 + 2 * p;
        const int rB = rA + 1;
        const int jrelA = rA + 1 + lane;           // [rA+1, rA+64]
        const int jrelB = rA + 65 + lane;          // [rA+65, rA+128]
        const unsigned* k1 = lds_kv + jrelA * SKB;
        const unsigned* k2 = lds_kv + jrelB * SKB;
        const float* qA = lds_q + rA * EE;
        const float* qB = lds_q + rB * EE;
        float sA1 = 0.f, sA2 = 0.f, sB1 = 0.f, sB2 = 0.f;
#pragma unroll
        for (int c = 0; c < 8; ++c) {              // 8 bf16 per iteration
            const uint4 a4 = *(const uint4*)(k1 + c * 4);
            const uint4 b4 = *(const uint4*)(k2 + c * 4);
            const float4 qa0 = *(const float4*)(qA + c * 8);       // broadcast
            const float4 qa1 = *(const float4*)(qA + c * 8 + 4);
            const float4 qb0 = *(const float4*)(qB + c * 8);
            const float4 qb1 = *(const float4*)(qB + c * 8 + 4);
            const float a0 = lo(a4.x), a1 = hi(a4.x), a2 = lo(a4.y), a3 = hi(a4.y);
            const float a4f = lo(a4.z), a5 = hi(a4.z), a6 = lo(a4.w), a7 = hi(a4.w);
            const float b0 = lo(b4.x), b1 = hi(b4.x), b2 = lo(b4.y), b3 = hi(b4.y);
            const float b4f = lo(b4.z), b5 = hi(b4.z), b6 = lo(b4.w), b7 = hi(b4.w);
            sA1 += qa0.x*a0 + qa0.y*a1 + qa0.z*a2 + qa0.w*a3
                 + qa1.x*a4f + qa1.y*a5 + qa1.z*a6 + qa1.w*a7;
            sA2 += qa0.x*b0 + qa0.y*b1 + qa0.z*b2 + qa0.w*b3
                 + qa1.x*b4f + qa1.y*b5 + qa1.z*b6 + qa1.w*b7;
            sB1 += qb0.x*a0 + qb0.y*a1 + qb0.z*a2 + qb0.w*a3
                 + qb1.x*a4f + qb1.y*a5 + qb1.z*a6 + qb1.w*a7;
            sB2 += qb0.x*b0 + qb0.y*b1 + qb0.z*b2 + qb0.w*b3
                 + qb1.x*b4f + qb1.y*b5 + qb1.z*b6 + qb1.w*b7;
        }
        const int jA = j0 + jrelA;   // global column of jrelA
        const int jB = j0 + jrelB;
        const bool vA1 = (jA >= 0);
        const bool vA2 = (lane <= 62) && (jB < LL);
        const bool vB1 = (lane >= 1) && (jA >= 0);
        const bool vB2 = (jB < LL);
        float eA1 = vA1 ? sA1 * scale : -3.0e38f;
        float eA2 = vA2 ? sA2 * scale : -3.0e38f;
        float eB1 = vB1 ? sB1 * scale : -3.0e38f;
        float eB2 = vB2 ? sB2 * scale : -3.0e38f;

        float mA = fmaxf(eA1, eA2);
        float mB = fmaxf(eB1, eB2);
#pragma unroll
        for (int off = 1; off < 64; off <<= 1) {
            mA = fmaxf(mA, __shfl_xor(mA, off, 64));
            mB = fmaxf(mB, __shfl_xor(mB, off, 64));
        }
        float pA1 = vA1 ? __expf(eA1 - mA) : 0.f;
        float pA2 = vA2 ? __expf(eA2 - mA) : 0.f;
        float pB1 = vB1 ? __expf(eB1 - mB) : 0.f;
        float pB2 = vB2 ? __expf(eB2 - mB) : 0.f;
        float lA = pA1 + pA2;
        float lB = pB1 + pB2;
#pragma unroll
        for (int off = 1; off < 64; off <<= 1) {
            lA += __shfl_xor(lA, off, 64);
            lB += __shfl_xor(lB, off, 64);
        }
        const float invA = 1.0f / lA;
        const float invB = 1.0f / lB;
        lds_sp[rA * PS + jrelA] = pA1 * invA;   // invalid lanes deposit exact 0
        lds_sp[rA * PS + jrelB] = pA2 * invA;
        lds_sp[rB * PS + jrelA] = pB1 * invB;
        lds_sp[rB * PS + jrelB] = pB2 * invB;
    }
    __syncthreads();   // all waves done reading lds_kv (K)

    // ---- Phase A2: stage V window (bf16) over lds_kv ----
    for (int idx = t; idx < WCAP * 16; idx += NT) {
        const int trow = idx >> 4, tf = idx & 15;
        int j = j0 + trow; j = j < 0 ? 0 : (j > LL - 1 ? LL - 1 : j);
        const float4 vv = *(const float4*)(V + headOff + (size_t)j * rowStr + tf * 4);
        uint2 pk; pk.x = pack2(vv.x, vv.y); pk.y = pack2(vv.z, vv.w);
        *(uint2*)(lds_kv + trow * SKB + tf * 2) = pk;
    }
    __syncthreads();

    // ---- Phase D: window-only stores (36 aligned f4 per row).           ----
    // Zeros are handled by the odd (zero) blocks.
    for (int r4 = 0; r4 < 4; ++r4) {
        const int r = wave * 4 + r4;
        float4* srow4 = (float4*)(srow0 + (size_t)r * LL);
        const float4* sp4 = (const float4*)(lds_sp + r * PS);
        if (lane < 36) {
            const int col4 = j04 + lane;
            if ((unsigned)col4 < (unsigned)(LL / 4))
                srow4[col4] = sp4[lane];
        }
    }

    // ---- Phase E: O[r,:] = sum_jrel P[r][jrel] * V[jrel,:]  (bf16 V)    ----
    {
        const int e4   = lane & 15;
        const int jsub = lane >> 4;
        const int rr0  = wave * 4;
        const float* pbase = lds_sp + rr0 * PS;
        float4 a0 = make_float4(0,0,0,0), a1 = a0, a2 = a0, a3 = a0;
#pragma unroll
        for (int k = 0; k < WCAP / 4; ++k) {
            const int jrel = jsub + 4 * k;   // 0..143
            const uint2 pv = *(const uint2*)(lds_kv + jrel * SKB + e4 * 2);
            const float v0 = lo(pv.x), v1 = hi(pv.x), v2 = lo(pv.y), v3 = hi(pv.y);
            const float w0 = pbase[jrel];                    // pads/invalid -> 0
            const float w1 = pbase[PS + jrel];
            const float w2 = pbase[2 * PS + jrel];
            const float w3 = pbase[3 * PS + jrel];
            a0.x += w0 * v0; a0.y += w0 * v1; a0.z += w0 * v2; a0.w += w0 * v3;
            a1.x += w1 * v0; a1.y += w1 * v1; a1.z += w1 * v2; a1.w += w1 * v3;
            a2.x += w2 * v0; a2.y += w2 * v1; a2.z += w2 * v2; a2.w += w2 * v3;
            a3.x += w3 * v0; a3.y += w3 * v1; a3.z += w3 * v2; a3.w += w3 * v3;
        }
#pragma unroll
        for (int off = 16; off <= 32; off <<= 1) {
            a0.x += __shfl_xor(a0.x, off, 64); a0.y += __shfl_xor(a0.y, off, 64);
            a0.z += __shfl_xor(a0.z, off, 64); a0.w += __shfl_xor(a0.w, off, 64);
            a1.x += __shfl_xor(a1.x, off, 64); a1.y += __shfl_xor(a1.y, off, 64);
            a1.z += __shfl_xor(a1.z, off, 64); a1.w += __shfl_xor(a1.w, off, 64);
            a2.x += __shfl_xor(a2.x, off, 64); a2.y += __shfl_xor(a2.y, off, 64);
            a2.z += __shfl_xor(a2.z, off, 64); a2.w += __shfl_xor(a2.w, off, 64);
            a3.x += __shfl_xor(a3.x, off, 64); a3.y += __shfl_xor(a3.y, off, 64);
            a3.z += __shfl_xor(a3.z, off, 64); a3.w += __shfl_xor(a3.w, off, 64);
        }
        if (lane < 16) {
            float4* o0 = (float4*)(outV + headOff + (size_t)(i0 + rr0 + 0) * rowStr);
            float4* o1 = (float4*)(outV + headOff + (size_t)(i0 + rr0 + 1) * rowStr);
            float4* o2 = (float4*)(outV + headOff + (size_t)(i0 + rr0 + 2) * rowStr);
            float4* o3 = (float4*)(outV + headOff + (size_t)(i0 + rr0 + 3) * rowStr);
            o0[e4] = a0; o1[e4] = a1; o2[e4] = a2; o3[e4] = a3;
        }
    }
}

extern "C" void kernel_launch(void* const* d_in, const int* in_sizes, int n_in,
                              void* d_out, int out_size, void* d_ws, size_t ws_size,
                              hipStream_t stream) {
    const float* Q = (const float*)d_in[0];
    const float* K = (const float*)d_in[1];
    const float* V = (const float*)d_in[2];
    // d_in[3] = sigma (unused by reference), d_in[4] = attn_mask (unused)

    float* outV = (float*)d_out;                                   // [B,L,H,E]
    float* outS = (float*)d_out + (size_t)BB * LL * HH * EE;       // [B,H,L,L]

    const int grid = 2 * (BB * HH * LL) / RR;  // 4096 blocks (compute+zero pairs)
    anomaly_attn_kernel<<<grid, NT, 0, stream>>>(Q, K, V, outV, outS);
}

// Round 14
// 331.685 us; speedup vs baseline: 1.0986x; 1.0986x over previous
//
#include <hip/hip_runtime.h>
#include <cstdint>

// Problem constants (fixed by the reference setup_inputs)
#define BB    2
#define LL    2048
#define HH    8
#define EE    64
#define DIAG  64
#define RR    16         // output rows per block
#define WCAP  144        // staged window rows: jrel 0..143 <-> j = i0-64 .. i0+79
#define SKB   36         // bf16 K/V tile row stride in DWORDS (32 data + 4 pad)
#define SQB   36         // bf16 Q tile row stride in DWORDS (16B-aligned rows)
#define PS    160        // prob/score row stride (floats), 16B-aligned
#define NT    256        // threads per block (4 waves)

typedef __attribute__((ext_vector_type(8))) short bf16x8;  // MFMA A/B frag
typedef __attribute__((ext_vector_type(4))) float f32x4;   // MFMA C/D

// One 256-thread block per 16 consecutive rows of one (b,h). 2048 blocks.
//
// R14: QK^T via v_mfma_f32_16x16x32_bf16 — kills Phase B's 96 ds_read_b128
// per wave (64 were Q broadcasts), the largest item in the ~44us/CU LDS-pipe
// budget that R9-R13 never attacked. D/E keep the best-measured R10 shape
// (full-row stores at the end: every store-redistribution attempt regressed).
// SPILL LESSON (R4-R7): no wide scalar-accumulator interleaves; MFMA accs are
// one f32x4 live at a time. WRITE-ONCE (R4): one compact full-row pass.
// MFMA layouts (verified, learn_hip m89/m120): A[m=lane&15][k=quad*8+j],
// B[k=quad*8+j][n=lane&15], C/D col=lane&15 row=quad*4+reg.
__global__ __launch_bounds__(NT, 4) void anomaly_attn_kernel(
    const float* __restrict__ Q,   // [B, L, H, E]
    const float* __restrict__ K,   // [B, L, H, E]
    const float* __restrict__ V,   // [B, L, H, E]
    float* __restrict__ outV,      // [B, L, H, E]
    float* __restrict__ outS)      // [B, H, L, L]
{
    __shared__ unsigned lds_k[WCAP * SKB];   // bf16 K tile, later V tile (20.7 KB)
    __shared__ unsigned lds_qb[RR * SQB];    // bf16 Q tile (2.3 KB)
    __shared__ float    lds_sp[RR * PS];     // raw scores -> probs (10 KB)
    // total 33.3 KB -> 4 blocks/CU

    // XCD swizzle: contiguous row-blocks per XCD for K/V L2 locality.
    const int bid  = blockIdx.x;
    const int gblk = (bid & 7) * 256 + (bid >> 3);   // [0, 2048)
    const int rb   = gblk & 127;
    const int h    = (gblk >> 7) & 7;
    const int b    = gblk >> 10;
    const int i0   = rb * RR;

    const int t    = threadIdx.x;
    const int wave = t >> 6;
    const int lane = t & 63;

    const size_t headOff = ((size_t)b * LL * HH + h) * EE;
    const int    rowStr  = HH * EE;   // 512 floats between sequence rows

    const int j0  = i0 - 64;          // jrel 0 <-> j = i0 - 64 (16-float aligned)
    const int j04 = j0 >> 2;

    float* srow0 = outS + (((size_t)(b * HH + h)) * LL + i0) * LL;

    // bf16 helpers (round-to-nearest-even pack; shift unpack)
    auto pack2 = [](float x, float y) -> unsigned {
        unsigned ux = __float_as_uint(x);
        unsigned uy = __float_as_uint(y);
        unsigned bx = (ux + 0x7FFFu + ((ux >> 16) & 1u)) >> 16;
        unsigned by = (uy + 0x7FFFu + ((uy >> 16) & 1u)) >> 16;
        return bx | (by << 16);
    };
    auto lo = [](unsigned u) -> float { return __uint_as_float(u << 16); };
    auto hi = [](unsigned u) -> float { return __uint_as_float(u & 0xFFFF0000u); };

    // ---- Phase A: stage Q (bf16) + K (bf16), rows clamped (masked later) ----
    {
        const int qrow = t >> 4, qf = t & 15;
        const float4 qv = *(const float4*)(Q + headOff + (size_t)(i0 + qrow) * rowStr + qf * 4);
        uint2 qp; qp.x = pack2(qv.x, qv.y); qp.y = pack2(qv.z, qv.w);
        *(uint2*)(lds_qb + qrow * SQB + qf * 2) = qp;
        for (int idx = t; idx < WCAP * 16; idx += NT) {
            const int trow = idx >> 4, tf = idx & 15;
            int j = j0 + trow; j = j < 0 ? 0 : (j > LL - 1 ? LL - 1 : j);
            const float4 kv = *(const float4*)(K + headOff + (size_t)j * rowStr + tf * 4);
            uint2 pk; pk.x = pack2(kv.x, kv.y); pk.y = pack2(kv.z, kv.w);
            *(uint2*)(lds_k + trow * SKB + tf * 2) = pk;
        }
    }
    __syncthreads();

    // ---- Phase B: scores via MFMA. Tile n covers jrel 16n..16n+15.      ----
    // Wave w owns tiles {w, w+4, w+8}. Raw (unscaled) scores -> lds_sp.
    {
        const int quad = lane >> 4;
        const int l16  = lane & 15;
        // A-frags: Q[m=l16][k = quad*8 + j], k-chunks 0 and 1 (k<32, k>=32)
        const bf16x8 a0 = *(const bf16x8*)(lds_qb + l16 * SQB + quad * 4);
        const bf16x8 a1 = *(const bf16x8*)(lds_qb + l16 * SQB + quad * 4 + 16);
        for (int n = wave; n < 9; n += 4) {
            const unsigned* kb = lds_k + (16 * n + l16) * SKB + quad * 4;
            const bf16x8 b0 = *(const bf16x8*)(kb);        // B[k][n'=l16] = K[16n+l16][k]
            const bf16x8 b1 = *(const bf16x8*)(kb + 16);
            f32x4 acc = {0.f, 0.f, 0.f, 0.f};
            acc = __builtin_amdgcn_mfma_f32_16x16x32_bf16(a0, b0, acc, 0, 0, 0);
            acc = __builtin_amdgcn_mfma_f32_16x16x32_bf16(a1, b1, acc, 0, 0, 0);
            // C/D: row = quad*4 + reg, col = 16n + l16
            float* dst = lds_sp + (quad * 4) * PS + 16 * n + l16;
            dst[0 * PS] = acc[0];
            dst[1 * PS] = acc[1];
            dst[2 * PS] = acc[2];
            dst[3 * PS] = acc[3];
        }
    }
    __syncthreads();   // scores from all waves' tiles visible

    // ---- Phase C: softmax in-place on lds_sp. Wave w owns rows 4w..4w+3. ----
    // Row r: band jrel in [r+1, r+127]; lane owns slots {lane, 64+lane,
    // 128+lane (lane<16)}. All 144 slots written unconditionally (invalid->0).
    const float scale = 0.125f;   // 1/sqrt(64)
    for (int r4 = 0; r4 < 4; ++r4) {
        const int r = wave * 4 + r4;
        float* sp = lds_sp + r * PS;
        const float x1 = sp[lane];
        const float x2 = sp[64 + lane];
        const float x3 = (lane < 16) ? sp[128 + lane] : 0.f;
        const bool v1 = (lane >= r + 1) && (j0 + lane >= 0);
        const bool v2 = (i0 + lane < LL);
        const bool v3 = (lane < 16) && (lane <= r - 1) && (i0 + 64 + lane < LL);
        float e1 = v1 ? x1 * scale : -3.0e38f;
        float e2 = v2 ? x2 * scale : -3.0e38f;
        float e3 = v3 ? x3 * scale : -3.0e38f;

        float m = fmaxf(e1, fmaxf(e2, e3));
#pragma unroll
        for (int off = 1; off < 64; off <<= 1)
            m = fmaxf(m, __shfl_xor(m, off, 64));
        float p1 = v1 ? __expf(e1 - m) : 0.f;
        float p2 = v2 ? __expf(e2 - m) : 0.f;
        float p3 = v3 ? __expf(e3 - m) : 0.f;
        float l = p1 + p2 + p3;
#pragma unroll
        for (int off = 1; off < 64; off <<= 1)
            l += __shfl_xor(l, off, 64);
        const float inv = 1.0f / l;
        sp[lane]      = p1 * inv;
        sp[64 + lane] = p2 * inv;
        if (lane < 16) sp[128 + lane] = p3 * inv;
    }

    // ---- Phase A2: stage V window (bf16) over lds_k (K reads all done). ----
    for (int idx = t; idx < WCAP * 16; idx += NT) {
        const int trow = idx >> 4, tf = idx & 15;
        int j = j0 + trow; j = j < 0 ? 0 : (j > LL - 1 ? LL - 1 : j);
        const float4 vv = *(const float4*)(V + headOff + (size_t)j * rowStr + tf * 4);
        uint2 pk; pk.x = pack2(vv.x, vv.y); pk.y = pack2(vv.z, vv.w);
        *(uint2*)(lds_k + trow * SKB + tf * 2) = pk;
    }

    // ---- Phase D: stream full series rows (R10 proven form, wave-local). ----
    {
        const int wstart4 = j04 < 0 ? 0 : j04;
        int wend4 = j04 + 36; if (wend4 > LL / 4) wend4 = LL / 4;
        for (int r4 = 0; r4 < 4; ++r4) {
            const int r = wave * 4 + r4;
            float4* srow4 = (float4*)(srow0 + (size_t)r * LL);
            const float4* sp4 = (const float4*)(lds_sp + r * PS);
#pragma unroll
            for (int k = 0; k < 8; ++k) {
                const int col4 = lane + k * 64;
                float4 v = make_float4(0.f, 0.f, 0.f, 0.f);
                if (col4 >= wstart4 && col4 < wend4)
                    v = sp4[col4 - j04];
                srow4[col4] = v;
            }
        }
    }
    __syncthreads();   // V tile staged for E

    // ---- Phase E: O[r,:] = sum_jrel P[r][jrel] * V[jrel,:]  (bf16 V)    ----
    {
        const int e4   = lane & 15;
        const int jsub = lane >> 4;
        const int rr0  = wave * 4;
        const float* pbase = lds_sp + rr0 * PS;
        float4 a0 = make_float4(0,0,0,0), a1 = a0, a2 = a0, a3 = a0;
#pragma unroll
        for (int k = 0; k < WCAP / 4; ++k) {
            const int jrel = jsub + 4 * k;   // 0..143
            const uint2 pv = *(const uint2*)(lds_k + jrel * SKB + e4 * 2);
            const float v0 = lo(pv.x), v1 = hi(pv.x), v2 = lo(pv.y), v3 = hi(pv.y);
            const float w0 = pbase[jrel];                    // invalid slots -> 0
            const float w1 = pbase[PS + jrel];
            const float w2 = pbase[2 * PS + jrel];
            const float w3 = pbase[3 * PS + jrel];
            a0.x += w0 * v0; a0.y += w0 * v1; a0.z += w0 * v2; a0.w += w0 * v3;
            a1.x += w1 * v0; a1.y += w1 * v1; a1.z += w1 * v2; a1.w += w1 * v3;
            a2.x += w2 * v0; a2.y += w2 * v1; a2.z += w2 * v2; a2.w += w2 * v3;
            a3.x += w3 * v0; a3.y += w3 * v1; a3.z += w3 * v2; a3.w += w3 * v3;
        }
#pragma unroll
        for (int off = 16; off <= 32; off <<= 1) {
            a0.x += __shfl_xor(a0.x, off, 64); a0.y += __shfl_xor(a0.y, off, 64);
            a0.z += __shfl_xor(a0.z, off, 64); a0.w += __shfl_xor(a0.w, off, 64);
            a1.x += __shfl_xor(a1.x, off, 64); a1.y += __shfl_xor(a1.y, off, 64);
            a1.z += __shfl_xor(a1.z, off, 64); a1.w += __shfl_xor(a1.w, off, 64);
            a2.x += __shfl_xor(a2.x, off, 64); a2.y += __shfl_xor(a2.y, off, 64);
            a2.z += __shfl_xor(a2.z, off, 64); a2.w += __shfl_xor(a2.w, off, 64);
            a3.x += __shfl_xor(a3.x, off, 64); a3.y += __shfl_xor(a3.y, off, 64);
            a3.z += __shfl_xor(a3.z, off, 64); a3.w += __shfl_xor(a3.w, off, 64);
        }
        if (lane < 16) {
            float4* o0 = (float4*)(outV + headOff + (size_t)(i0 + rr0 + 0) * rowStr);
            float4* o1 = (float4*)(outV + headOff + (size_t)(i0 + rr0 + 1) * rowStr);
            float4* o2 = (float4*)(outV + headOff + (size_t)(i0 + rr0 + 2) * rowStr);
            float4* o3 = (float4*)(outV + headOff + (size_t)(i0 + rr0 + 3) * rowStr);
            o0[e4] = a0; o1[e4] = a1; o2[e4] = a2; o3[e4] = a3;
        }
    }
}

extern "C" void kernel_launch(void* const* d_in, const int* in_sizes, int n_in,
                              void* d_out, int out_size, void* d_ws, size_t ws_size,
                              hipStream_t stream) {
    const float* Q = (const float*)d_in[0];
    const float* K = (const float*)d_in[1];
    const float* V = (const float*)d_in[2];
    // d_in[3] = sigma (unused by reference), d_in[4] = attn_mask (unused)

    float* outV = (float*)d_out;                                   // [B,L,H,E]
    float* outS = (float*)d_out + (size_t)BB * LL * HH * EE;       // [B,H,L,L]

    const int grid = (BB * HH * LL) / RR;  // 2048 blocks
    anomaly_attn_kernel<<<grid, NT, 0, stream>>>(Q, K, V, outV, outS);
}